// Round 2
// baseline (159.550 us; speedup 1.0000x reference)
//
#include <hip/hip_runtime.h>

// Output of reference = haar_wavedec(x, 3) only; the MLP (psi) is dead code.
// x: (B=128, C=128, L=1024) fp32. Rows = B*C = 16384, each of length L=1024.
// Out layout (flat, return order): a3[NR][L/8], d3[NR][L/8], d2[NR][L/4], d1[NR][L/2].
// One thread per 8 consecutive input elements => fully independent butterfly.

constexpr int L = 1024;
constexpr int TPR = L / 8;           // threads per row = 128
constexpr float C_INV_SQRT2 = 0.7071067811865476f;

__global__ __launch_bounds__(256) void haar3_kernel(const float* __restrict__ x,
                                                    float* __restrict__ out,
                                                    int n_rows) {
    const int t = blockIdx.x * blockDim.x + threadIdx.x;
    const int total = n_rows * TPR;
    if (t >= total) return;

    const float c = C_INV_SQRT2;
    const float4 v0 = reinterpret_cast<const float4*>(x)[2 * (size_t)t];
    const float4 v1 = reinterpret_cast<const float4*>(x)[2 * (size_t)t + 1];

    // Level 1 (match reference association order exactly: (e +/- o) * c)
    const float a10 = (v0.x + v0.y) * c;
    const float a11 = (v0.z + v0.w) * c;
    const float a12 = (v1.x + v1.y) * c;
    const float a13 = (v1.z + v1.w) * c;
    float4 d1;
    d1.x = (v0.x - v0.y) * c;
    d1.y = (v0.z - v0.w) * c;
    d1.z = (v1.x - v1.y) * c;
    d1.w = (v1.z - v1.w) * c;

    // Level 2
    const float a20 = (a10 + a11) * c;
    const float a21 = (a12 + a13) * c;
    float2 d2;
    d2.x = (a10 - a11) * c;
    d2.y = (a12 - a13) * c;

    // Level 3
    const float a3 = (a20 + a21) * c;
    const float d3 = (a20 - a21) * c;

    const size_t NR = (size_t)n_rows;
    // a3 region: elements [0, NR*TPR). Thread t's row r = t/TPR, k = t%TPR;
    // linear index r*TPR + k == t. Same collapse holds for every region.
    out[t] = a3;
    out[NR * TPR + t] = d3;
    reinterpret_cast<float2*>(out + NR * TPR * 2)[t] = d2;  // row stride L/4 = TPR float2s
    reinterpret_cast<float4*>(out + NR * TPR * 4)[t] = d1;  // row stride L/2 = TPR float4s
}

extern "C" void kernel_launch(void* const* d_in, const int* in_sizes, int n_in,
                              void* d_out, int out_size, void* d_ws, size_t ws_size,
                              hipStream_t stream) {
    const float* x = (const float*)d_in[0];
    float* out = (float*)d_out;
    const int n_rows = in_sizes[0] / L;          // 128*128 = 16384
    const int total_threads = n_rows * TPR;      // 2,097,152
    const int block = 256;
    const int grid = (total_threads + block - 1) / block;  // 8192
    haar3_kernel<<<grid, block, 0, stream>>>(x, out, n_rows);
}